// Round 1
// baseline (370.925 us; speedup 1.0000x reference)
//
#include <hip/hip_runtime.h>
#include <hip/hip_bf16.h>

typedef __attribute__((ext_vector_type(8))) short bf16x8;
typedef __attribute__((ext_vector_type(4))) float f32x4;

__device__ __forceinline__ ushort bf16rne(float f) {
    uint u = __float_as_uint(f);
    return (ushort)((u + 0x7fffu + ((u >> 16) & 1u)) >> 16);
}
__device__ __forceinline__ void unpack2(uint p, float& a, float& b) {
    a = __uint_as_float(p << 16);
    b = __uint_as_float(p & 0xffff0000u);
}

// ---------------- merged castT + bucket histogram ----------------
// blocks 0..151: weight transpose+cast. blocks 152..: bucket histogram.

__global__ __launch_bounds__(256) void k_pre1(const float* __restrict__ W1,
                                              const float* __restrict__ Wm,
                                              const float* __restrict__ W2,
                                              ushort* __restrict__ w1t,
                                              ushort* __restrict__ wmt,
                                              ushort* __restrict__ w2t,
                                              const int* __restrict__ dst,
                                              int* __restrict__ bcnt, int E) {
    __shared__ int hist[512];
    int b = blockIdx.x;
    int t = threadIdx.x;
    if (b < 152) {
        if (b < 64) {
            int i = b * 256 + t; int k = i >> 7, n = i & 127;
            w1t[n * 128 + k] = bf16rne(W1[k * 128 + n]);
        } else if (b < 128) {
            int i = (b - 64) * 256 + t; int k = i >> 7, n = i & 127;
            wmt[n * 128 + k] = bf16rne(Wm[k * 128 + n]);
        } else {
            int i = (b - 128) * 256 + t;
            if (i < 6144) {
                int n = i >> 7, k = i & 127;
                w2t[n * 128 + k] = (n < 40) ? bf16rne(W2[k * 40 + n]) : (ushort)0;
            }
        }
        return;
    }
    hist[t] = 0; hist[t + 256] = 0;
    __syncthreads();
    int off = (b - 152) * 4096;
    int cnt = min(4096, E - off);
    for (int i = t; i < cnt; i += 256) atomicAdd(&hist[dst[off + i] >> 8], 1);
    __syncthreads();
    if (hist[t]) atomicAdd(&bcnt[t], hist[t]);
    if (hist[t + 256]) atomicAdd(&bcnt[t + 256], hist[t + 256]);
}

__global__ void k_bscan(const int* __restrict__ bcnt, int* __restrict__ bbase,
                        int* __restrict__ bcur, int nbuck) {
    __shared__ int s[512];
    int t = threadIdx.x;  // 512
    s[t] = (t < nbuck) ? bcnt[t] : 0;
    __syncthreads();
    for (int d = 1; d < 512; d <<= 1) {
        int u = (t >= d) ? s[t - d] : 0;
        __syncthreads();
        if (t >= d) s[t] += u;
        __syncthreads();
    }
    int excl = (t == 0) ? 0 : s[t - 1];
    bbase[t] = excl;
    if (t < nbuck) bcur[t] = excl;
    if (t == 511) bbase[512] = s[511];
}

// ---------------- merged binpack + layer-1 GEMM (unscaled output) ----------------

__global__ __launch_bounds__(256) void k_pack_gemm(const int* __restrict__ src,
                                                   const int* __restrict__ dst,
                                                   int* __restrict__ bcur,
                                                   uint* __restrict__ pairbuf,
                                                   int E, int nbuck, int ntile,
                                                   const float* __restrict__ A,
                                                   const ushort* __restrict__ Wt,
                                                   ushort* __restrict__ C, int M) {
    __shared__ int hist[512];
    __shared__ int scn[512];
    __shared__ int cur[512];
    __shared__ int gbase[512];
    __shared__ uint sorted[4096];
    int t = threadIdx.x;
    if ((int)blockIdx.x >= ntile) {
        // ---- gemm1 body (unscaled out) ----
        int blk = blockIdx.x - ntile;
        int wave = t >> 6, lane = t & 63;
        int m16 = lane & 15, quad = lane >> 4;
        int rowA = blk * 64 + wave * 16 + m16;
        int rA = min(rowA, M - 1);
        const float4* A4 = (const float4*)A;

        f32x4 acc[8];
#pragma unroll
        for (int i = 0; i < 8; i++) acc[i] = (f32x4){0.f, 0.f, 0.f, 0.f};
#pragma unroll
        for (int it = 0; it < 4; it++) {
            float4 f0 = A4[(size_t)rA * 32 + 8 * it + 2 * quad];
            float4 f1 = A4[(size_t)rA * 32 + 8 * it + 2 * quad + 1];
            bf16x8 af;
            af[0] = (short)bf16rne(f0.x); af[1] = (short)bf16rne(f0.y);
            af[2] = (short)bf16rne(f0.z); af[3] = (short)bf16rne(f0.w);
            af[4] = (short)bf16rne(f1.x); af[5] = (short)bf16rne(f1.y);
            af[6] = (short)bf16rne(f1.z); af[7] = (short)bf16rne(f1.w);
#pragma unroll
            for (int nt = 0; nt < 8; nt++) {
                bf16x8 bfr = *(const bf16x8*)(Wt + (size_t)(nt * 16 + m16) * 128 + it * 32 + quad * 8);
                acc[nt] = __builtin_amdgcn_mfma_f32_16x16x32_bf16(af, bfr, acc[nt], 0, 0, 0);
            }
        }
        int rowBase = blk * 64 + wave * 16 + quad * 4;
#pragma unroll
        for (int nt = 0; nt < 8; nt++) {
            int col = nt * 16 + m16;
#pragma unroll
            for (int r = 0; r < 4; r++) {
                int row = rowBase + r;
                if (row < M) C[(size_t)row * 128 + col] = bf16rne(acc[nt][r]);
            }
        }
        return;
    }
    // ---- binpack body ----
    int off = blockIdx.x * 4096;
    int cnt = min(4096, E - off);
    hist[t] = 0; hist[t + 256] = 0;
    __syncthreads();
    for (int i = t; i < cnt; i += 256) {
        int b = dst[off + i] >> 8;
        atomicAdd(&hist[b], 1);
    }
    __syncthreads();
    scn[t] = hist[t]; scn[t + 256] = hist[t + 256];
    __syncthreads();
    for (int d = 1; d < 256; d <<= 1) {
        int u0 = (t >= d) ? scn[t - d] : 0;
        int u1 = (t >= d) ? scn[256 + t - d] : 0;
        __syncthreads();
        if (t >= d) { scn[t] += u0; scn[256 + t] += u1; }
        __syncthreads();
    }
    int tot0 = scn[255];
    scn[256 + t] += tot0;
    __syncthreads();
    cur[t] = (t == 0) ? 0 : scn[t - 1];
    cur[t + 256] = scn[t + 255];
    if (t < nbuck && hist[t] > 0) gbase[t] = atomicAdd(&bcur[t], hist[t]);
    int t2 = t + 256;
    if (t2 < nbuck && hist[t2] > 0) gbase[t2] = atomicAdd(&bcur[t2], hist[t2]);
    __syncthreads();
    for (int i = t; i < cnt; i += 256) {
        int d = dst[off + i];
        int s = src[off + i];
        int b = d >> 8;
        int pos = atomicAdd(&cur[b], 1);
        sorted[pos] = ((uint)(d & 255) << 24) | (uint)s;
    }
    __syncthreads();
    int wid = t >> 6, lane = t & 63;
    for (int b = wid; b < nbuck; b += 4) {
        int n = hist[b];
        if (n == 0) continue;
        int ls = (b == 0) ? 0 : scn[b - 1];
        int gb = gbase[b];
        for (int j = lane; j < n; j += 64)
            pairbuf[gb + j] = sorted[ls + j];
    }
}

#define CSR_CAP 5632
__global__ __launch_bounds__(256) void k_csrbuild(const uint* __restrict__ pairbuf,
                                                  const int* __restrict__ bbase,
                                                  int* __restrict__ rowptr,
                                                  float* __restrict__ dinv,
                                                  int* __restrict__ csr,
                                                  int N, int nbuck) {
    __shared__ int lhist[256];
    __shared__ int scn[256];
    __shared__ int lcur[256];
    __shared__ int lcsr[CSR_CAP];
    int b = blockIdx.x;
    int base = b << 8;
    int nn = min(256, N - base);
    int lo = bbase[b], hi = bbase[b + 1];
    int cnt = hi - lo;
    int t = threadIdx.x;
    lhist[t] = 0;
    __syncthreads();
    for (int i = t; i < cnt; i += 256) atomicAdd(&lhist[pairbuf[lo + i] >> 24], 1);
    __syncthreads();
    int mydeg = lhist[t];
    scn[t] = mydeg;
    __syncthreads();
    for (int d = 1; d < 256; d <<= 1) {
        int u = (t >= d) ? scn[t - d] : 0;
        __syncthreads();
        if (t >= d) scn[t] += u;
        __syncthreads();
    }
    int excl = (t == 0) ? 0 : scn[t - 1];
    lcur[t] = excl;
    if (t < nn) {
        rowptr[base + t] = lo + excl;
        dinv[base + t] = rsqrtf((float)(mydeg + 1));  // +1 = self-loop
    }
    if (b == nbuck - 1 && t == 0) rowptr[N] = hi;
    __syncthreads();
    if (cnt <= CSR_CAP) {
        for (int i = t; i < cnt; i += 256) {
            uint p = pairbuf[lo + i];
            int pos = atomicAdd(&lcur[p >> 24], 1);
            lcsr[pos] = (int)(p & 0xFFFFFFu);
        }
        __syncthreads();
        for (int i = t; i < cnt; i += 256) csr[lo + i] = lcsr[i];
    } else {
        for (int i = t; i < cnt; i += 256) {
            uint p = pairbuf[lo + i];
            int pos = lo + atomicAdd(&lcur[p >> 24], 1);
            csr[pos] = (int)(p & 0xFFFFFFu);
        }
    }
}

// ---------------- fused agg + GEMM ----------------
// Agg restructure (R1): ONE NODE PER WAVE, 64 lanes x 1 uint (2 bf16 cols).
//  - zero exec-mask divergence (old 16-lane-group scheme wasted ~30% of gather
//    slots on degree imbalance across the 4 groups of a wave)
//  - csr indices + dinv[s] weights loaded 64-at-a-time coalesced, then
//    broadcast per-edge via v_readlane -> row base lives in SGPR, gather is
//    global_load_dword v, v_laneoff, s[base] with no per-edge VGPR addr chain
//  - 8 row-gathers (2 KB) in flight per wave
// EDGE_W=true: input g UNSCALED -> per-edge dinv[s] weights (layer 1 only).
// Both write the GEMM output PRE-SCALED by dinv[row] (R12 convention).

template <int NT, bool EDGE_W>
__device__ __forceinline__ void fused_agg_gemm(const ushort* __restrict__ g,
                                               const float* __restrict__ dinv,
                                               const int* __restrict__ rowptr,
                                               const int* __restrict__ csr,
                                               const float* __restrict__ bias,
                                               const ushort* __restrict__ Wt,
                                               ushort* __restrict__ C,
                                               int M, int ccols) {
    __shared__ ushort hs[32][136];
    __shared__ int nextNode;
    int t = threadIdx.x;
    if (t == 0) nextNode = 0;
    __syncthreads();
    int lane = t & 63;
    const uint* g32 = (const uint*)g;
    float2 bb = ((const float2*)bias)[lane];

    for (;;) {
        int idx = 0;
        if (lane == 0) idx = atomicAdd(&nextNode, 1);
        idx = __builtin_amdgcn_readfirstlane(idx);
        if (idx >= 32) break;
        int node = blockIdx.x * 32 + idx;
        int nd = min(node, M - 1);
        float dn = dinv[nd];
        int e0 = rowptr[nd], e1 = rowptr[nd + 1];
        float a0, a1;
        {
            uint p = g32[(size_t)nd * 64 + lane];
            float u, v;
            unpack2(p, u, v);
            if (EDGE_W) { a0 = u * dn; a1 = v * dn; } else { a0 = u; a1 = v; }
        }
        for (int base = e0; base < e1; base += 64) {
            int nchunk = e1 - base;
            if (nchunk > 64) nchunk = 64;
            int sidx = 0;
            int swi = 0x3f800000;
            if (lane < nchunk) {
                sidx = csr[base + lane];
                if (EDGE_W) swi = __float_as_int(dinv[sidx]);
            }
            int j = 0;
            for (; j + 8 <= nchunk; j += 8) {
                int s0 = __builtin_amdgcn_readlane(sidx, j);
                int s1 = __builtin_amdgcn_readlane(sidx, j + 1);
                int s2 = __builtin_amdgcn_readlane(sidx, j + 2);
                int s3 = __builtin_amdgcn_readlane(sidx, j + 3);
                int s4 = __builtin_amdgcn_readlane(sidx, j + 4);
                int s5 = __builtin_amdgcn_readlane(sidx, j + 5);
                int s6 = __builtin_amdgcn_readlane(sidx, j + 6);
                int s7 = __builtin_amdgcn_readlane(sidx, j + 7);
                uint p0 = g32[(size_t)s0 * 64 + lane];
                uint p1 = g32[(size_t)s1 * 64 + lane];
                uint p2 = g32[(size_t)s2 * 64 + lane];
                uint p3 = g32[(size_t)s3 * 64 + lane];
                uint p4 = g32[(size_t)s4 * 64 + lane];
                uint p5 = g32[(size_t)s5 * 64 + lane];
                uint p6 = g32[(size_t)s6 * 64 + lane];
                uint p7 = g32[(size_t)s7 * 64 + lane];
                float u, v;
                if (EDGE_W) {
                    float w0 = __int_as_float(__builtin_amdgcn_readlane(swi, j));
                    float w1 = __int_as_float(__builtin_amdgcn_readlane(swi, j + 1));
                    float w2 = __int_as_float(__builtin_amdgcn_readlane(swi, j + 2));
                    float w3 = __int_as_float(__builtin_amdgcn_readlane(swi, j + 3));
                    float w4 = __int_as_float(__builtin_amdgcn_readlane(swi, j + 4));
                    float w5 = __int_as_float(__builtin_amdgcn_readlane(swi, j + 5));
                    float w6 = __int_as_float(__builtin_amdgcn_readlane(swi, j + 6));
                    float w7 = __int_as_float(__builtin_amdgcn_readlane(swi, j + 7));
                    unpack2(p0, u, v); a0 += u * w0; a1 += v * w0;
                    unpack2(p1, u, v); a0 += u * w1; a1 += v * w1;
                    unpack2(p2, u, v); a0 += u * w2; a1 += v * w2;
                    unpack2(p3, u, v); a0 += u * w3; a1 += v * w3;
                    unpack2(p4, u, v); a0 += u * w4; a1 += v * w4;
                    unpack2(p5, u, v); a0 += u * w5; a1 += v * w5;
                    unpack2(p6, u, v); a0 += u * w6; a1 += v * w6;
                    unpack2(p7, u, v); a0 += u * w7; a1 += v * w7;
                } else {
                    unpack2(p0, u, v); a0 += u; a1 += v;
                    unpack2(p1, u, v); a0 += u; a1 += v;
                    unpack2(p2, u, v); a0 += u; a1 += v;
                    unpack2(p3, u, v); a0 += u; a1 += v;
                    unpack2(p4, u, v); a0 += u; a1 += v;
                    unpack2(p5, u, v); a0 += u; a1 += v;
                    unpack2(p6, u, v); a0 += u; a1 += v;
                    unpack2(p7, u, v); a0 += u; a1 += v;
                }
            }
            for (; j < nchunk; j++) {
                int s0 = __builtin_amdgcn_readlane(sidx, j);
                uint p0 = g32[(size_t)s0 * 64 + lane];
                float u, v;
                unpack2(p0, u, v);
                if (EDGE_W) {
                    float w0 = __int_as_float(__builtin_amdgcn_readlane(swi, j));
                    a0 += u * w0; a1 += v * w0;
                } else {
                    a0 += u; a1 += v;
                }
            }
        }
        float o0 = fmaxf(a0 * dn + bb.x, 0.f);
        float o1 = fmaxf(a1 * dn + bb.y, 0.f);
        uint q = (uint)bf16rne(o0) | ((uint)bf16rne(o1) << 16);
        *(uint*)&hs[idx][lane * 2] = q;
    }
    __syncthreads();

    // GEMM from LDS: 4 waves = 2 row-halves x 2 n-tile-halves; PRE-SCALED out.
    int wave = t >> 6, lane6 = t & 63;
    int m16 = lane6 & 15, quad = lane6 >> 4;
    int rowHalf = wave & 1;
    int ntHalf = wave >> 1;
    constexpr int NTH = (NT + 1) / 2;
    int ntStart = ntHalf * NTH;
    int ntEnd = ntHalf ? NT : NTH;

    f32x4 acc[NTH];
#pragma unroll
    for (int i = 0; i < NTH; i++) acc[i] = (f32x4){0.f, 0.f, 0.f, 0.f};
#pragma unroll
    for (int it = 0; it < 4; it++) {
        bf16x8 af = *(const bf16x8*)&hs[rowHalf * 16 + m16][it * 32 + quad * 8];
        for (int nt = ntStart; nt < ntEnd; nt++) {
            bf16x8 bfr = *(const bf16x8*)(Wt + (size_t)(nt * 16 + m16) * 128 + it * 32 + quad * 8);
            acc[nt - ntStart] = __builtin_amdgcn_mfma_f32_16x16x32_bf16(af, bfr, acc[nt - ntStart], 0, 0, 0);
        }
    }
    int rowBase = blockIdx.x * 32 + rowHalf * 16 + quad * 4;
    float dnv[4];
#pragma unroll
    for (int r = 0; r < 4; r++) dnv[r] = dinv[min(rowBase + r, M - 1)];
    for (int nt = ntStart; nt < ntEnd; nt++) {
        int col = nt * 16 + m16;
        if (col >= ccols) continue;
#pragma unroll
        for (int r = 0; r < 4; r++) {
            int row = rowBase + r;
            if (row < M) C[(size_t)row * ccols + col] = bf16rne(acc[nt - ntStart][r] * dnv[r]);
        }
    }
}

__global__ __launch_bounds__(256) void k_fusedA(const ushort* __restrict__ g,
                                                const float* __restrict__ dinv,
                                                const int* __restrict__ rowptr,
                                                const int* __restrict__ csr,
                                                const float* __restrict__ bias,
                                                const ushort* __restrict__ Wt,
                                                ushort* __restrict__ C, int M) {
    fused_agg_gemm<8, true>(g, dinv, rowptr, csr, bias, Wt, C, M, 128);  // unscaled in
}

__global__ __launch_bounds__(256) void k_fusedB(const ushort* __restrict__ g,
                                                const float* __restrict__ dinv,
                                                const int* __restrict__ rowptr,
                                                const int* __restrict__ csr,
                                                const float* __restrict__ bias,
                                                const ushort* __restrict__ Wt,
                                                ushort* __restrict__ C, int M) {
    fused_agg_gemm<3, false>(g, dinv, rowptr, csr, bias, Wt, C, M, 40);  // pre-scaled in
}

// ---------------- final aggregation over 40-col rows (pre-scaled g3) ----------------

__global__ __launch_bounds__(256) void k_agg40_b(const ushort* __restrict__ g3,
                                                 const float* __restrict__ dinv,
                                                 const int* __restrict__ rowptr,
                                                 const int* __restrict__ csr,
                                                 const float* __restrict__ bias,
                                                 float* __restrict__ out, int N) {
    int t = threadIdx.x;
    if (t >= 250) return;
    int grp = t / 10;
    int l = t - grp * 10;
    int node = blockIdx.x * 25 + grp;
    if (node >= N) return;
    const uint2* gp = (const uint2*)g3;
    float dn = dinv[node];
    float a0, a1, a2, a3;
    {
        uint2 p = gp[(size_t)node * 10 + l];
        unpack2(p.x, a0, a1);
        unpack2(p.y, a2, a3);
    }
    int e0 = rowptr[node], e1 = rowptr[node + 1];
    int e = e0;
    for (; e + 4 <= e1; e += 4) {
        int s0 = csr[e], s1 = csr[e + 1], s2 = csr[e + 2], s3 = csr[e + 3];
        uint2 p0 = gp[(size_t)s0 * 10 + l];
        uint2 p1 = gp[(size_t)s1 * 10 + l];
        uint2 p2 = gp[(size_t)s2 * 10 + l];
        uint2 p3 = gp[(size_t)s3 * 10 + l];
        float u, v;
        unpack2(p0.x, u, v); a0 += u; a1 += v;
        unpack2(p0.y, u, v); a2 += u; a3 += v;
        unpack2(p1.x, u, v); a0 += u; a1 += v;
        unpack2(p1.y, u, v); a2 += u; a3 += v;
        unpack2(p2.x, u, v); a0 += u; a1 += v;
        unpack2(p2.y, u, v); a2 += u; a3 += v;
        unpack2(p3.x, u, v); a0 += u; a1 += v;
        unpack2(p3.y, u, v); a2 += u; a3 += v;
    }
    for (; e < e1; e++) {
        int s = csr[e];
        uint2 p = gp[(size_t)s * 10 + l];
        float u, v;
        unpack2(p.x, u, v); a0 += u; a1 += v;
        unpack2(p.y, u, v); a2 += u; a3 += v;
    }
    float4 bb = ((const float4*)bias)[l];
    float4 o;
    o.x = a0 * dn + bb.x;
    o.y = a1 * dn + bb.y;
    o.z = a2 * dn + bb.z;
    o.w = a3 * dn + bb.w;
    ((float4*)out)[(size_t)node * 10 + l] = o;
}

// ---------------- launch ----------------

extern "C" void kernel_launch(void* const* d_in, const int* in_sizes, int n_in,
                              void* d_out, int out_size, void* d_ws, size_t ws_size,
                              hipStream_t stream) {
    const float* x  = (const float*)d_in[0];
    const int* eidx = (const int*)d_in[1];
    const float* W1 = (const float*)d_in[2];
    const float* b1 = (const float*)d_in[3];
    const float* Wm = (const float*)d_in[4];
    const float* bm = (const float*)d_in[5];
    const float* W2 = (const float*)d_in[6];
    const float* b2 = (const float*)d_in[7];
    float* out = (float*)d_out;

    int N = in_sizes[0] / 128;
    int E = in_sizes[1] / 2;
    const int* src = eidx;
    const int* dst = eidx + E;
    int nbuck = (N + 255) >> 8;
    int ntile = (E + 4095) / 4096;

    char* ws = (char*)d_ws;
    size_t off = 0;
    auto alloc = [&](size_t bytes) -> void* {
        void* p = ws + off;
        off += (bytes + 255) & ~(size_t)255;
        return p;
    };
    float*  dinv    = (float*)alloc((size_t)N * 4);
    int*    rowptr  = (int*)alloc(((size_t)N + 1) * 4);
    int*    csr     = (int*)alloc((size_t)E * 4);
    uint*   pairbuf = (uint*)alloc((size_t)E * 4);
    int*    bcnt    = (int*)alloc(512 * 4);
    int*    bbase   = (int*)alloc(513 * 4);
    int*    bcur    = (int*)alloc(512 * 4);
    ushort* w1t     = (ushort*)alloc(128 * 128 * 2);
    ushort* wmt     = (ushort*)alloc(128 * 128 * 2);
    ushort* w2t     = (ushort*)alloc(48 * 128 * 2);
    ushort* gbuf    = (ushort*)alloc((size_t)N * 128 * 2);  // layer-1 out, UNSCALED
    ushort* gbuf2   = (ushort*)alloc((size_t)N * 128 * 2);  // layer-2 out, pre-scaled
    ushort* g3      = (ushort*)alloc((size_t)N * 40 * 2);   // layer-3 out, pre-scaled

    int gblk64 = (N + 63) / 64;
    int gblk32 = (N + 31) / 32;

    hipMemsetAsync(bcnt, 0, 512 * 4, stream);
    // castT (152 blocks) || bhist (ntile blocks)
    k_pre1<<<152 + ntile, 256, 0, stream>>>(W1, Wm, W2, w1t, wmt, w2t, dst, bcnt, E);
    k_bscan<<<1, 512, 0, stream>>>(bcnt, bbase, bcur, nbuck);
    // binpack (ntile blocks) || gemm1 (gblk64 blocks, unscaled output)
    k_pack_gemm<<<ntile + gblk64, 256, 0, stream>>>(src, dst, bcur, pairbuf, E, nbuck,
                                                    ntile, x, w1t, gbuf, N);
    k_csrbuild<<<nbuck, 256, 0, stream>>>(pairbuf, bbase, rowptr, dinv, csr, N, nbuck);
    // layer-1 agg (per-edge dinv on unscaled gbuf) + layer-2 GEMM (pre-scaled out)
    k_fusedA<<<gblk32, 256, 0, stream>>>(gbuf, dinv, rowptr, csr, b1, wmt, gbuf2, N);
    // layer-2 agg (pre-scaled, plain adds) + layer-3 GEMM (pre-scaled out)
    k_fusedB<<<gblk32, 256, 0, stream>>>(gbuf2, dinv, rowptr, csr, bm, w2t, g3, N);
    // final aggregation
    k_agg40_b<<<(N + 24) / 25, 256, 0, stream>>>(g3, dinv, rowptr, csr, b2, out, N);
}

// Round 2
// 357.628 us; speedup vs baseline: 1.0372x; 1.0372x over previous
//
#include <hip/hip_runtime.h>
#include <hip/hip_bf16.h>

typedef __attribute__((ext_vector_type(8))) short bf16x8;
typedef __attribute__((ext_vector_type(4))) float f32x4;

__device__ __forceinline__ ushort bf16rne(float f) {
    uint u = __float_as_uint(f);
    return (ushort)((u + 0x7fffu + ((u >> 16) & 1u)) >> 16);
}
__device__ __forceinline__ void unpack2(uint p, float& a, float& b) {
    a = __uint_as_float(p << 16);
    b = __uint_as_float(p & 0xffff0000u);
}

// ---------------- merged castT + bucket histogram ----------------
// blocks 0..151: weight transpose+cast. blocks 152..: bucket histogram.

__global__ __launch_bounds__(256) void k_pre1(const float* __restrict__ W1,
                                              const float* __restrict__ Wm,
                                              const float* __restrict__ W2,
                                              ushort* __restrict__ w1t,
                                              ushort* __restrict__ wmt,
                                              ushort* __restrict__ w2t,
                                              const int* __restrict__ dst,
                                              int* __restrict__ bcnt, int E) {
    __shared__ int hist[512];
    int b = blockIdx.x;
    int t = threadIdx.x;
    if (b < 152) {
        if (b < 64) {
            int i = b * 256 + t; int k = i >> 7, n = i & 127;
            w1t[n * 128 + k] = bf16rne(W1[k * 128 + n]);
        } else if (b < 128) {
            int i = (b - 64) * 256 + t; int k = i >> 7, n = i & 127;
            wmt[n * 128 + k] = bf16rne(Wm[k * 128 + n]);
        } else {
            int i = (b - 128) * 256 + t;
            if (i < 6144) {
                int n = i >> 7, k = i & 127;
                w2t[n * 128 + k] = (n < 40) ? bf16rne(W2[k * 40 + n]) : (ushort)0;
            }
        }
        return;
    }
    hist[t] = 0; hist[t + 256] = 0;
    __syncthreads();
    int off = (b - 152) * 4096;
    int cnt = min(4096, E - off);
    for (int i = t; i < cnt; i += 256) atomicAdd(&hist[dst[off + i] >> 8], 1);
    __syncthreads();
    if (hist[t]) atomicAdd(&bcnt[t], hist[t]);
    if (hist[t + 256]) atomicAdd(&bcnt[t + 256], hist[t + 256]);
}

__global__ void k_bscan(const int* __restrict__ bcnt, int* __restrict__ bbase,
                        int* __restrict__ bcur, int nbuck) {
    __shared__ int s[512];
    int t = threadIdx.x;  // 512
    s[t] = (t < nbuck) ? bcnt[t] : 0;
    __syncthreads();
    for (int d = 1; d < 512; d <<= 1) {
        int u = (t >= d) ? s[t - d] : 0;
        __syncthreads();
        if (t >= d) s[t] += u;
        __syncthreads();
    }
    int excl = (t == 0) ? 0 : s[t - 1];
    bbase[t] = excl;
    if (t < nbuck) bcur[t] = excl;
    if (t == 511) bbase[512] = s[511];
}

// ---------------- merged binpack + layer-1 GEMM (unscaled output) ----------------

__global__ __launch_bounds__(256) void k_pack_gemm(const int* __restrict__ src,
                                                   const int* __restrict__ dst,
                                                   int* __restrict__ bcur,
                                                   uint* __restrict__ pairbuf,
                                                   int E, int nbuck, int ntile,
                                                   const float* __restrict__ A,
                                                   const ushort* __restrict__ Wt,
                                                   ushort* __restrict__ C, int M) {
    __shared__ int hist[512];
    __shared__ int scn[512];
    __shared__ int cur[512];
    __shared__ int gbase[512];
    __shared__ uint sorted[4096];
    int t = threadIdx.x;
    if ((int)blockIdx.x >= ntile) {
        // ---- gemm1 body (unscaled out) ----
        int blk = blockIdx.x - ntile;
        int wave = t >> 6, lane = t & 63;
        int m16 = lane & 15, quad = lane >> 4;
        int rowA = blk * 64 + wave * 16 + m16;
        int rA = min(rowA, M - 1);
        const float4* A4 = (const float4*)A;

        f32x4 acc[8];
#pragma unroll
        for (int i = 0; i < 8; i++) acc[i] = (f32x4){0.f, 0.f, 0.f, 0.f};
#pragma unroll
        for (int it = 0; it < 4; it++) {
            float4 f0 = A4[(size_t)rA * 32 + 8 * it + 2 * quad];
            float4 f1 = A4[(size_t)rA * 32 + 8 * it + 2 * quad + 1];
            bf16x8 af;
            af[0] = (short)bf16rne(f0.x); af[1] = (short)bf16rne(f0.y);
            af[2] = (short)bf16rne(f0.z); af[3] = (short)bf16rne(f0.w);
            af[4] = (short)bf16rne(f1.x); af[5] = (short)bf16rne(f1.y);
            af[6] = (short)bf16rne(f1.z); af[7] = (short)bf16rne(f1.w);
#pragma unroll
            for (int nt = 0; nt < 8; nt++) {
                bf16x8 bfr = *(const bf16x8*)(Wt + (size_t)(nt * 16 + m16) * 128 + it * 32 + quad * 8);
                acc[nt] = __builtin_amdgcn_mfma_f32_16x16x32_bf16(af, bfr, acc[nt], 0, 0, 0);
            }
        }
        int rowBase = blk * 64 + wave * 16 + quad * 4;
#pragma unroll
        for (int nt = 0; nt < 8; nt++) {
            int col = nt * 16 + m16;
#pragma unroll
            for (int r = 0; r < 4; r++) {
                int row = rowBase + r;
                if (row < M) C[(size_t)row * 128 + col] = bf16rne(acc[nt][r]);
            }
        }
        return;
    }
    // ---- binpack body ----
    int off = blockIdx.x * 4096;
    int cnt = min(4096, E - off);
    hist[t] = 0; hist[t + 256] = 0;
    __syncthreads();
    for (int i = t; i < cnt; i += 256) {
        int b = dst[off + i] >> 8;
        atomicAdd(&hist[b], 1);
    }
    __syncthreads();
    scn[t] = hist[t]; scn[t + 256] = hist[t + 256];
    __syncthreads();
    for (int d = 1; d < 256; d <<= 1) {
        int u0 = (t >= d) ? scn[t - d] : 0;
        int u1 = (t >= d) ? scn[256 + t - d] : 0;
        __syncthreads();
        if (t >= d) { scn[t] += u0; scn[256 + t] += u1; }
        __syncthreads();
    }
    int tot0 = scn[255];
    scn[256 + t] += tot0;
    __syncthreads();
    cur[t] = (t == 0) ? 0 : scn[t - 1];
    cur[t + 256] = scn[t + 255];
    if (t < nbuck && hist[t] > 0) gbase[t] = atomicAdd(&bcur[t], hist[t]);
    int t2 = t + 256;
    if (t2 < nbuck && hist[t2] > 0) gbase[t2] = atomicAdd(&bcur[t2], hist[t2]);
    __syncthreads();
    for (int i = t; i < cnt; i += 256) {
        int d = dst[off + i];
        int s = src[off + i];
        int b = d >> 8;
        int pos = atomicAdd(&cur[b], 1);
        sorted[pos] = ((uint)(d & 255) << 24) | (uint)s;
    }
    __syncthreads();
    int wid = t >> 6, lane = t & 63;
    for (int b = wid; b < nbuck; b += 4) {
        int n = hist[b];
        if (n == 0) continue;
        int ls = (b == 0) ? 0 : scn[b - 1];
        int gb = gbase[b];
        for (int j = lane; j < n; j += 64)
            pairbuf[gb + j] = sorted[ls + j];
    }
}

#define CSR_CAP 5632
__global__ __launch_bounds__(256) void k_csrbuild(const uint* __restrict__ pairbuf,
                                                  const int* __restrict__ bbase,
                                                  int* __restrict__ rowptr,
                                                  float* __restrict__ dinv,
                                                  int* __restrict__ csr,
                                                  int N, int nbuck) {
    __shared__ int lhist[256];
    __shared__ int scn[256];
    __shared__ int lcur[256];
    __shared__ int lcsr[CSR_CAP];
    int b = blockIdx.x;
    int base = b << 8;
    int nn = min(256, N - base);
    int lo = bbase[b], hi = bbase[b + 1];
    int cnt = hi - lo;
    int t = threadIdx.x;
    lhist[t] = 0;
    __syncthreads();
    for (int i = t; i < cnt; i += 256) atomicAdd(&lhist[pairbuf[lo + i] >> 24], 1);
    __syncthreads();
    int mydeg = lhist[t];
    scn[t] = mydeg;
    __syncthreads();
    for (int d = 1; d < 256; d <<= 1) {
        int u = (t >= d) ? scn[t - d] : 0;
        __syncthreads();
        if (t >= d) scn[t] += u;
        __syncthreads();
    }
    int excl = (t == 0) ? 0 : scn[t - 1];
    lcur[t] = excl;
    if (t < nn) {
        rowptr[base + t] = lo + excl;
        dinv[base + t] = rsqrtf((float)(mydeg + 1));  // +1 = self-loop
    }
    if (b == nbuck - 1 && t == 0) rowptr[N] = hi;
    __syncthreads();
    if (cnt <= CSR_CAP) {
        for (int i = t; i < cnt; i += 256) {
            uint p = pairbuf[lo + i];
            int pos = atomicAdd(&lcur[p >> 24], 1);
            lcsr[pos] = (int)(p & 0xFFFFFFu);
        }
        __syncthreads();
        for (int i = t; i < cnt; i += 256) csr[lo + i] = lcsr[i];
    } else {
        for (int i = t; i < cnt; i += 256) {
            uint p = pairbuf[lo + i];
            int pos = lo + atomicAdd(&lcur[p >> 24], 1);
            csr[pos] = (int)(p & 0xFFFFFFu);
        }
    }
}

// ---------------- fused agg + GEMM ----------------
// Agg (R2): TWO nodes per wave per claim, interleaved edge streams.
//  - 64 lanes x 1 uint (2 bf16 cols) per row; zero divergence (all control
//    uniform: nc/j are SGPR values, csr/dinv index loads lane-predicated only)
//  - indices+weights broadcast via v_readlane (land in SGPRs)
//  - ALL edges processed as weighted 8-batches, zero-padded to x8 (pad lanes
//    gather row 0 with weight 0 -> no scalar-serial tail loads)
//  - 16 gathers (4 KB) in flight per wave: B-stream issues while A consumes
// EDGE_W=true: input g UNSCALED -> per-edge dinv[s] weights (layer 1 only).
// Both write the GEMM output PRE-SCALED by dinv[row].

template <bool EDGE_W>
__device__ __forceinline__ void agg_issue8(const uint* __restrict__ g32, int lane,
                                           int sidx, int swi, int j,
                                           uint P[8], float W[8]) {
#pragma unroll
    for (int k = 0; k < 8; k++) {
        int s = __builtin_amdgcn_readlane(sidx, j + k);
        W[k] = __int_as_float(__builtin_amdgcn_readlane(swi, j + k));
        P[k] = g32[(size_t)s * 64 + lane];
    }
}
__device__ __forceinline__ void agg_consume8(const uint P[8], const float W[8],
                                             float& a0, float& a1) {
#pragma unroll
    for (int k = 0; k < 8; k++) {
        float u, v;
        unpack2(P[k], u, v);
        a0 += u * W[k];
        a1 += v * W[k];
    }
}

template <int NT, bool EDGE_W>
__device__ __forceinline__ void fused_agg_gemm(const ushort* __restrict__ g,
                                               const float* __restrict__ dinv,
                                               const int* __restrict__ rowptr,
                                               const int* __restrict__ csr,
                                               const float* __restrict__ bias,
                                               const ushort* __restrict__ Wt,
                                               ushort* __restrict__ C,
                                               int M, int ccols) {
    __shared__ ushort hs[32][136];
    __shared__ int nextNode;
    int t = threadIdx.x;
    if (t == 0) nextNode = 0;
    __syncthreads();
    int lane = t & 63;
    const uint* g32 = (const uint*)g;
    float2 bb = ((const float2*)bias)[lane];

    for (;;) {
        int idx0 = 0;
        if (lane == 0) idx0 = atomicAdd(&nextNode, 2);
        idx0 = __builtin_amdgcn_readfirstlane(idx0);
        if (idx0 >= 32) break;
        int ndA = min(blockIdx.x * 32 + idx0, M - 1);
        int ndB = min(blockIdx.x * 32 + idx0 + 1, M - 1);
        float dnA = dinv[ndA], dnB = dinv[ndB];
        int e0A = rowptr[ndA], e1A = rowptr[ndA + 1];
        int e0B = rowptr[ndB], e1B = rowptr[ndB + 1];
        uint pSA = g32[(size_t)ndA * 64 + lane];
        uint pSB = g32[(size_t)ndB * 64 + lane];
        float a0, a1, b0, b1;
        {
            float u, v;
            unpack2(pSA, u, v);
            if (EDGE_W) { a0 = u * dnA; a1 = v * dnA; } else { a0 = u; a1 = v; }
            unpack2(pSB, u, v);
            if (EDGE_W) { b0 = u * dnB; b1 = v * dnB; } else { b0 = u; b1 = v; }
        }
        int baseA = e0A, baseB = e0B;
        while (baseA < e1A || baseB < e1B) {
            int ncA = e1A - baseA; if (ncA > 64) ncA = 64;
            int ncB = e1B - baseB; if (ncB > 64) ncB = 64;
            // load index/weight chunks; pad lanes: sidx=0 (row 0, L1-hot), w=0
            int sidxA = 0, swiA = 0, sidxB = 0, swiB = 0;
            if (lane < ncA) {
                sidxA = csr[baseA + lane];
                swiA = EDGE_W ? __float_as_int(dinv[sidxA]) : 0x3f800000;
            }
            if (lane < ncB) {
                sidxB = csr[baseB + lane];
                swiB = EDGE_W ? __float_as_int(dinv[sidxB]) : 0x3f800000;
            }
            int nc8A = (ncA + 7) & ~7;
            int nc8B = (ncB + 7) & ~7;
            int jA = 0, jB = 0;
            while (jA < nc8A && jB < nc8B) {
                uint PA[8], PB[8];
                float WA[8], WB[8];
                agg_issue8<EDGE_W>(g32, lane, sidxA, swiA, jA, PA, WA);
                agg_issue8<EDGE_W>(g32, lane, sidxB, swiB, jB, PB, WB);
                agg_consume8(PA, WA, a0, a1);
                agg_consume8(PB, WB, b0, b1);
                jA += 8; jB += 8;
            }
            while (jA < nc8A) {
                uint PA[8]; float WA[8];
                agg_issue8<EDGE_W>(g32, lane, sidxA, swiA, jA, PA, WA);
                agg_consume8(PA, WA, a0, a1);
                jA += 8;
            }
            while (jB < nc8B) {
                uint PB[8]; float WB[8];
                agg_issue8<EDGE_W>(g32, lane, sidxB, swiB, jB, PB, WB);
                agg_consume8(PB, WB, b0, b1);
                jB += 8;
            }
            baseA += ncA;
            baseB += ncB;
        }
        float o0 = fmaxf(a0 * dnA + bb.x, 0.f);
        float o1 = fmaxf(a1 * dnA + bb.y, 0.f);
        float o2 = fmaxf(b0 * dnB + bb.x, 0.f);
        float o3 = fmaxf(b1 * dnB + bb.y, 0.f);
        uint qA = (uint)bf16rne(o0) | ((uint)bf16rne(o1) << 16);
        uint qB = (uint)bf16rne(o2) | ((uint)bf16rne(o3) << 16);
        *(uint*)&hs[idx0][lane * 2] = qA;
        *(uint*)&hs[idx0 + 1][lane * 2] = qB;
    }
    __syncthreads();

    // GEMM from LDS: 4 waves = 2 row-halves x 2 n-tile-halves; PRE-SCALED out.
    int wave = t >> 6, lane6 = t & 63;
    int m16 = lane6 & 15, quad = lane6 >> 4;
    int rowHalf = wave & 1;
    int ntHalf = wave >> 1;
    constexpr int NTH = (NT + 1) / 2;
    int ntStart = ntHalf * NTH;
    int ntEnd = ntHalf ? NT : NTH;

    f32x4 acc[NTH];
#pragma unroll
    for (int i = 0; i < NTH; i++) acc[i] = (f32x4){0.f, 0.f, 0.f, 0.f};
#pragma unroll
    for (int it = 0; it < 4; it++) {
        bf16x8 af = *(const bf16x8*)&hs[rowHalf * 16 + m16][it * 32 + quad * 8];
        for (int nt = ntStart; nt < ntEnd; nt++) {
            bf16x8 bfr = *(const bf16x8*)(Wt + (size_t)(nt * 16 + m16) * 128 + it * 32 + quad * 8);
            acc[nt - ntStart] = __builtin_amdgcn_mfma_f32_16x16x32_bf16(af, bfr, acc[nt - ntStart], 0, 0, 0);
        }
    }
    int rowBase = blockIdx.x * 32 + rowHalf * 16 + quad * 4;
    float dnv[4];
#pragma unroll
    for (int r = 0; r < 4; r++) dnv[r] = dinv[min(rowBase + r, M - 1)];
    for (int nt = ntStart; nt < ntEnd; nt++) {
        int col = nt * 16 + m16;
        if (col >= ccols) continue;
#pragma unroll
        for (int r = 0; r < 4; r++) {
            int row = rowBase + r;
            if (row < M) C[(size_t)row * ccols + col] = bf16rne(acc[nt - ntStart][r] * dnv[r]);
        }
    }
}

__global__ __launch_bounds__(256) void k_fusedA(const ushort* __restrict__ g,
                                                const float* __restrict__ dinv,
                                                const int* __restrict__ rowptr,
                                                const int* __restrict__ csr,
                                                const float* __restrict__ bias,
                                                const ushort* __restrict__ Wt,
                                                ushort* __restrict__ C, int M) {
    fused_agg_gemm<8, true>(g, dinv, rowptr, csr, bias, Wt, C, M, 128);  // unscaled in
}

__global__ __launch_bounds__(256) void k_fusedB(const ushort* __restrict__ g,
                                                const float* __restrict__ dinv,
                                                const int* __restrict__ rowptr,
                                                const int* __restrict__ csr,
                                                const float* __restrict__ bias,
                                                const ushort* __restrict__ Wt,
                                                ushort* __restrict__ C, int M) {
    fused_agg_gemm<3, false>(g, dinv, rowptr, csr, bias, Wt, C, M, 40);  // pre-scaled in
}

// ---------------- final aggregation over 40-col rows (pre-scaled g3) ----------------

__global__ __launch_bounds__(256) void k_agg40_b(const ushort* __restrict__ g3,
                                                 const float* __restrict__ dinv,
                                                 const int* __restrict__ rowptr,
                                                 const int* __restrict__ csr,
                                                 const float* __restrict__ bias,
                                                 float* __restrict__ out, int N) {
    int t = threadIdx.x;
    if (t >= 250) return;
    int grp = t / 10;
    int l = t - grp * 10;
    int node = blockIdx.x * 25 + grp;
    if (node >= N) return;
    const uint2* gp = (const uint2*)g3;
    float dn = dinv[node];
    float a0, a1, a2, a3;
    {
        uint2 p = gp[(size_t)node * 10 + l];
        unpack2(p.x, a0, a1);
        unpack2(p.y, a2, a3);
    }
    int e0 = rowptr[node], e1 = rowptr[node + 1];
    int e = e0;
    for (; e + 4 <= e1; e += 4) {
        int s0 = csr[e], s1 = csr[e + 1], s2 = csr[e + 2], s3 = csr[e + 3];
        uint2 p0 = gp[(size_t)s0 * 10 + l];
        uint2 p1 = gp[(size_t)s1 * 10 + l];
        uint2 p2 = gp[(size_t)s2 * 10 + l];
        uint2 p3 = gp[(size_t)s3 * 10 + l];
        float u, v;
        unpack2(p0.x, u, v); a0 += u; a1 += v;
        unpack2(p0.y, u, v); a2 += u; a3 += v;
        unpack2(p1.x, u, v); a0 += u; a1 += v;
        unpack2(p1.y, u, v); a2 += u; a3 += v;
        unpack2(p2.x, u, v); a0 += u; a1 += v;
        unpack2(p2.y, u, v); a2 += u; a3 += v;
        unpack2(p3.x, u, v); a0 += u; a1 += v;
        unpack2(p3.y, u, v); a2 += u; a3 += v;
    }
    for (; e < e1; e++) {
        int s = csr[e];
        uint2 p = gp[(size_t)s * 10 + l];
        float u, v;
        unpack2(p.x, u, v); a0 += u; a1 += v;
        unpack2(p.y, u, v); a2 += u; a3 += v;
    }
    float4 bb = ((const float4*)bias)[l];
    float4 o;
    o.x = a0 * dn + bb.x;
    o.y = a1 * dn + bb.y;
    o.z = a2 * dn + bb.z;
    o.w = a3 * dn + bb.w;
    ((float4*)out)[(size_t)node * 10 + l] = o;
}

// ---------------- launch ----------------

extern "C" void kernel_launch(void* const* d_in, const int* in_sizes, int n_in,
                              void* d_out, int out_size, void* d_ws, size_t ws_size,
                              hipStream_t stream) {
    const float* x  = (const float*)d_in[0];
    const int* eidx = (const int*)d_in[1];
    const float* W1 = (const float*)d_in[2];
    const float* b1 = (const float*)d_in[3];
    const float* Wm = (const float*)d_in[4];
    const float* bm = (const float*)d_in[5];
    const float* W2 = (const float*)d_in[6];
    const float* b2 = (const float*)d_in[7];
    float* out = (float*)d_out;

    int N = in_sizes[0] / 128;
    int E = in_sizes[1] / 2;
    const int* src = eidx;
    const int* dst = eidx + E;
    int nbuck = (N + 255) >> 8;
    int ntile = (E + 4095) / 4096;

    char* ws = (char*)d_ws;
    size_t off = 0;
    auto alloc = [&](size_t bytes) -> void* {
        void* p = ws + off;
        off += (bytes + 255) & ~(size_t)255;
        return p;
    };
    float*  dinv    = (float*)alloc((size_t)N * 4);
    int*    rowptr  = (int*)alloc(((size_t)N + 1) * 4);
    int*    csr     = (int*)alloc((size_t)E * 4);
    uint*   pairbuf = (uint*)alloc((size_t)E * 4);
    int*    bcnt    = (int*)alloc(512 * 4);
    int*    bbase   = (int*)alloc(513 * 4);
    int*    bcur    = (int*)alloc(512 * 4);
    ushort* w1t     = (ushort*)alloc(128 * 128 * 2);
    ushort* wmt     = (ushort*)alloc(128 * 128 * 2);
    ushort* w2t     = (ushort*)alloc(48 * 128 * 2);
    ushort* gbuf    = (ushort*)alloc((size_t)N * 128 * 2);  // layer-1 out, UNSCALED
    ushort* gbuf2   = (ushort*)alloc((size_t)N * 128 * 2);  // layer-2 out, pre-scaled
    ushort* g3      = (ushort*)alloc((size_t)N * 40 * 2);   // layer-3 out, pre-scaled

    int gblk64 = (N + 63) / 64;
    int gblk32 = (N + 31) / 32;

    hipMemsetAsync(bcnt, 0, 512 * 4, stream);
    // castT (152 blocks) || bhist (ntile blocks)
    k_pre1<<<152 + ntile, 256, 0, stream>>>(W1, Wm, W2, w1t, wmt, w2t, dst, bcnt, E);
    k_bscan<<<1, 512, 0, stream>>>(bcnt, bbase, bcur, nbuck);
    // binpack (ntile blocks) || gemm1 (gblk64 blocks, unscaled output)
    k_pack_gemm<<<ntile + gblk64, 256, 0, stream>>>(src, dst, bcur, pairbuf, E, nbuck,
                                                    ntile, x, w1t, gbuf, N);
    k_csrbuild<<<nbuck, 256, 0, stream>>>(pairbuf, bbase, rowptr, dinv, csr, N, nbuck);
    // layer-1 agg (per-edge dinv on unscaled gbuf) + layer-2 GEMM (pre-scaled out)
    k_fusedA<<<gblk32, 256, 0, stream>>>(gbuf, dinv, rowptr, csr, b1, wmt, gbuf2, N);
    // layer-2 agg (pre-scaled, plain adds) + layer-3 GEMM (pre-scaled out)
    k_fusedB<<<gblk32, 256, 0, stream>>>(gbuf2, dinv, rowptr, csr, bm, w2t, g3, N);
    // final aggregation
    k_agg40_b<<<(N + 24) / 25, 256, 0, stream>>>(g3, dinv, rowptr, csr, b2, out, N);
}